// Round 15
// baseline (119.208 us; speedup 1.0000x reference)
//
#include <hip/hip_runtime.h>
#include <stdint.h>

#define DEV static __device__ __forceinline__

typedef __attribute__((ext_vector_type(4))) float f32x4;
typedef __attribute__((ext_vector_type(16))) float f32x16;
typedef __attribute__((ext_vector_type(8))) short bf16x8;               // 8 bf16 in 4 VGPR (guide §3)
typedef bf16x8 __attribute__((may_alias)) bf16x8_a;
typedef __attribute__((ext_vector_type(2))) unsigned int u32x2;
typedef u32x2 __attribute__((may_alias)) u32x2_a;

// f32 -> bf16 RNE, manual bit math (PROVEN; round-6's inline-asm cvt_pk NaN'd)
DEV unsigned short f2bf(float f) {
  union { float f; unsigned int u; } v; v.f = f;
  return (unsigned short)((v.u + 0x7FFFu + ((v.u >> 16) & 1u)) >> 16);
}

DEV float bf2f(unsigned short s) {
  union { unsigned int u; float f; } v; v.u = ((unsigned int)s) << 16;
  return v.f;
}

DEV float fast_exp2(float x) {            // native v_exp_f32 = 2^x
  float r;
  asm("v_exp_f32 %0, %1" : "=v"(r) : "v"(x));
  return r;
}

// pack two POSITIVE f32 -> (bf16_trunc(hi)<<16)|bf16_trunc(lo), ONE v_perm_b32.
// Truncation error cancels in O/l since the l-denominator (MFMA rowsum) is computed
// from the SAME truncated values.
DEV unsigned int pktrunc(float lo, float hi) {
  union { float f; unsigned int u; } a, b; a.f = lo; b.f = hi;
  return __builtin_amdgcn_perm(b.u, a.u, 0x07060302u);  // bytes: b3 b2 a3 a2
}

DEV void gload_lds16(const void* g, void* l) {
  __builtin_amdgcn_global_load_lds(
      (const __attribute__((address_space(1))) unsigned int*)g,
      (__attribute__((address_space(3))) unsigned int*)l, 16, 0, 0);
}

// ---------------- fused prep kernel: cast + 2 transposes in one launch ----------------
DEV void transpose_body(const float* __restrict__ in, unsigned short* __restrict__ out,
                        int R, int C, int bx, int by, int t, float (*tile)[33]) {
  const int r = t >> 3, c4 = (t & 7) << 2;
  const int tr = by << 5, tc = bx << 5;
  const float4 v = *(const float4*)(in + (size_t)(tr + r) * C + tc + c4);
  tile[r][c4] = v.x; tile[r][c4 + 1] = v.y; tile[r][c4 + 2] = v.z; tile[r][c4 + 3] = v.w;
  __syncthreads();
  ushort4 o;
  o.x = f2bf(tile[c4][r]); o.y = f2bf(tile[c4 + 1][r]);
  o.z = f2bf(tile[c4 + 2][r]); o.w = f2bf(tile[c4 + 3][r]);
  *(ushort4*)(out + (size_t)(tc + r) * R + tr + c4) = o;
}

__global__ __launch_bounds__(256) void prep_k(const float4* __restrict__ q4,
                                              ushort4* __restrict__ Xb,
                                              const float* __restrict__ Wqkv,
                                              unsigned short* __restrict__ WqkvT,
                                              const float* __restrict__ Wout,
                                              unsigned short* __restrict__ WoutT) {
  __shared__ float tile[32][33];
  const int t = threadIdx.x, bid = blockIdx.x;
  if (bid < 4096) {                       // cast query fp32 -> bf16 (4M elems)
    const int i = bid * 256 + t;
    float4 f = q4[i];
    ushort4 o; o.x = f2bf(f.x); o.y = f2bf(f.y); o.z = f2bf(f.z); o.w = f2bf(f.w);
    Xb[i] = o;
  } else if (bid < 4096 + 3072) {         // W_qkv [1024][3072] -> bf16 [3072][1024]
    const int id = bid - 4096;
    transpose_body(Wqkv, WqkvT, 1024, 3072, id % 96, id / 96, t, tile);
  } else {                                // W_out [1024][1024] -> bf16 [1024][1024]^T
    const int id = bid - 4096 - 3072;
    transpose_body(Wout, WoutT, 1024, 1024, id & 31, id >> 5, t, tile);
  }
}

// ---------------- GEMM (m97/m103 structure): C[M,N] = A[M,K] * BT[N,K]^T ----------------
// TM=128 x BN, BK=64, SINGLE-buffered LDS, 2 barriers/iter — the 912 TF @4096^3
// structure (m103). 4 waves as 2x2; 32 MFMA + 16 b128 per wave per K-step.
// Chunk-XOR swizzle (rule #21). XCD swizzle: bid%8 = XCD owns 4 m-panels.
// EPI==1 scatter: q (x0.125*log2e) / k [B,H,S,64] / vT [B,H,64,S] with kv bit2<->3
// swap (tau) matching attn's 32x32 in-register P layout.
template <int EPI, int BN>
__global__ __launch_bounds__(256, 3) void gemm_bt(const unsigned short* __restrict__ A,
                                                  const unsigned short* __restrict__ BT,
                                                  const float* __restrict__ bias,
                                                  float* __restrict__ Cout,
                                                  unsigned short* __restrict__ q_buf,
                                                  unsigned short* __restrict__ k_buf,
                                                  unsigned short* __restrict__ vT_buf,
                                                  int M, int N, int K) {
  constexpr int NI = BN / 32;                   // n-frags per wave (wave grid 2x2)
  constexpr int NW = BN / 2;                    // cols per wave
  __shared__ unsigned short As[128 * 64];       // 16 KB, chunk-swizzled
  __shared__ unsigned short Bs[BN * 64];        // 16 or 8 KB
  const int t = threadIdx.x, w = t >> 6, l = t & 63;
  const int wm = w >> 1, wn = w & 1;
  const int lg = l >> 4, ln = l & 15;

  const int xcd = blockIdx.x & 7, jb = blockIdx.x >> 3;
  const int m0 = (xcd * 4 + (jb & 3)) * 128;    // 32 m-panels = 8 XCD x 4
  const int n0 = (jb >> 2) * BN;

  // staging: thread covers 16B chunk; row = (t>>3)+j*32, source chunk inverse-swizzled
  const int sch = (t & 7) ^ ((t >> 3) & 7);

  f32x4 acc[4][NI] = {};

#define STAGE97(k0)                                                                      \
  do {                                                                                   \
    _Pragma("unroll")                                                                    \
    for (int j = 0; j < 4; ++j)                                                          \
      gload_lds16(A + (size_t)(m0 + (t >> 3) + j * 32) * K + (k0) + sch * 8,             \
                  &As[((t >> 3) + j * 32) * 64 + (t & 7) * 8]);                          \
    _Pragma("unroll")                                                                    \
    for (int j = 0; j < BN / 32; ++j)                                                    \
      gload_lds16(BT + (size_t)(n0 + (t >> 3) + j * 32) * K + (k0) + sch * 8,            \
                  &Bs[((t >> 3) + j * 32) * 64 + (t & 7) * 8]);                          \
  } while (0)

  for (int kt = 0; kt < K; kt += 64) {
    STAGE97(kt);
    __syncthreads();                     // vmcnt drained -> tile resident
#pragma unroll
    for (int kk = 0; kk < 2; ++kk) {
      bf16x8 af[4], bfr[NI];
#pragma unroll
      for (int mi = 0; mi < 4; ++mi)
        af[mi] = *(const bf16x8_a*)&As[(wm * 64 + mi * 16 + ln) * 64 +
                                       (((kk * 4 + lg) ^ (ln & 7)) << 3)];
#pragma unroll
      for (int ni = 0; ni < NI; ++ni)
        bfr[ni] = *(const bf16x8_a*)&Bs[(wn * NW + ni * 16 + ln) * 64 +
                                        (((kk * 4 + lg) ^ (ln & 7)) << 3)];
#pragma unroll
      for (int mi = 0; mi < 4; ++mi)
#pragma unroll
        for (int ni = 0; ni < NI; ++ni)
          acc[mi][ni] = __builtin_amdgcn_mfma_f32_16x16x32_bf16(af[mi], bfr[ni], acc[mi][ni], 0, 0, 0);
    }
    __syncthreads();                     // reads done -> tile reusable
  }
#undef STAGE97

  // epilogue: C/D layout col = lane&15, row = (lane>>4)*4 + reg  (m89-verified)
#pragma unroll
  for (int ni = 0; ni < NI; ++ni) {
    const int c = n0 + wn * NW + ni * 16 + ln;
    const float bv = bias[c];
    if (EPI == 1) {
      const int which = c >> 10;          // 0:q 1:k 2:v   (wave-uniform)
      const int h = (c >> 6) & 15;
      const int d = c & 63;
#pragma unroll
      for (int mi = 0; mi < 4; ++mi) {
        const int mrow = m0 + wm * 64 + mi * 16 + lg * 4;
        const int b = mrow >> 11, s = mrow & 2047;
        const size_t bh = (size_t)(b * 16 + h);
        f32x4 v = acc[mi][ni];
        if (which == 0) {
          const float QSCALE = 0.125f * 1.44269504088896340736f;  // hd^-0.5 * log2(e)
          unsigned short* dst = q_buf + (bh * 2048 + s) * 64 + d;
#pragma unroll
          for (int r = 0; r < 4; ++r) dst[(size_t)r * 64] = f2bf((v[r] + bv) * QSCALE);
        } else if (which == 1) {
          unsigned short* dst = k_buf + (bh * 2048 + s) * 64 + d;
#pragma unroll
          for (int r = 0; r < 4; ++r) dst[(size_t)r * 64] = f2bf(v[r] + bv);
        } else {
          // tau: swap bits 2<->3 of within-tile kv index (keeps 4-contiguity, s%4==0)
          const int sp = (s & ~12) | ((s & 4) << 1) | ((s & 8) >> 1);
          unsigned short* dst = vT_buf + (bh * 64 + d) * 2048 + sp;
          ushort4 o4;
          o4.x = f2bf(v[0] + bv); o4.y = f2bf(v[1] + bv); o4.z = f2bf(v[2] + bv); o4.w = f2bf(v[3] + bv);
          *(ushort4*)dst = o4;
        }
      }
    } else {
#pragma unroll
      for (int mi = 0; mi < 4; ++mi) {
        const int mrow = m0 + wm * 64 + mi * 16 + lg * 4;
        f32x4 v = acc[mi][ni];
#pragma unroll
        for (int r = 0; r < 4; ++r) Cout[(size_t)(mrow + r) * N + c] = v[r] + bv;
      }
    }
  }
}

// ---------------- flash attention (round 15: BISECT — r12 arithmetic + setprio only) ----------------
// Round-14 failed (absmax 2.2e-2) after bundling {no-shift, setprio}. This round
// restores the SHIFT=-16 arithmetic EXACTLY as round 12 (passing, 46us) and keeps
// ONLY setprio. The no-shift change was mathematically scale-invariant but changed
// codegen (v_exp_f32 inline asm consuming MFMA accumulators directly, no interposed
// v_add — rule-#18 territory); never retry without on-device verification.
// Structure: 32x32 swapped QK^T, in-register P, MFMA rowsum, 32 q-rows/wave,
// 4 blocks/CU, dbuf K/V in LDS, XOR swizzle, XCD swizzle.
template <int SPLIT>
__global__ __launch_bounds__(256, 4) void attn_k(const unsigned short* __restrict__ Qb,
                                                 const unsigned short* __restrict__ Kb,
                                                 const unsigned short* __restrict__ Vt,
                                                 unsigned short* __restrict__ AO,
                                                 unsigned short* __restrict__ Opart,
                                                 float* __restrict__ lpart) {
  constexpr int NT = 32 / SPLIT;              // KV tiles per block
  const float SHIFT = -16.0f;                 // static softmax shift (exact; scores ~N(0,1.44^2))
  __shared__ unsigned short Ks[2][64 * 64];   // 16 KB
  __shared__ unsigned short Vs[2][64 * 64];   // 16 KB  (kv columns in tau-order)

  const int t = threadIdx.x, w = t >> 6, l = t & 63;
  const int l31 = l & 31, lh = l >> 5;
  const int xcd = blockIdx.x & 7, idx = blockIdx.x >> 3;
  const int bh = xcd * 4 + (idx & 3);                    // [0,32)
  const int qt = (SPLIT == 2) ? ((idx >> 2) & 15) : (idx >> 2);
  const int half = (SPLIT == 2) ? (idx >> 6) : 0;
  const int b = bh >> 4, h = bh & 15;
  const unsigned short* Q = Qb + (size_t)bh * 2048 * 64;
  const unsigned short* K = Kb + (size_t)bh * 2048 * 64 + (size_t)half * NT * 64 * 64;
  const unsigned short* V = Vt + (size_t)bh * 64 * 2048 + half * NT * 64;
  const int qbase = qt * 128 + w * 32;

  const int srow = t >> 3;                                // 0..31 (+32 second chunk)
  const int scol = ((t & 7) ^ (srow & 7)) << 3;           // swizzled source col
  const int dcol = (t & 7) << 3;                          // linear LDS col

  // Q fragments (B-operand): lane holds q-col = l31, d = kd*16 + lh*8 + 0..7
  bf16x8 qf[4];
#pragma unroll
  for (int kd = 0; kd < 4; ++kd)
    qf[kd] = *(const bf16x8_a*)(Q + (size_t)(qbase + l31) * 64 + kd * 16 + lh * 8);

  bf16x8 ones;
#pragma unroll
  for (int i = 0; i < 8; ++i) ones[i] = (short)0x3F80;    // bf16 1.0

  f32x16 o32[2] = {};
  f32x16 lsum = {};

  {
    gload_lds16(K + (size_t)srow * 64 + scol,        &Ks[0][srow * 64 + dcol]);
    gload_lds16(K + (size_t)(srow + 32) * 64 + scol, &Ks[0][(srow + 32) * 64 + dcol]);
    gload_lds16(V + (size_t)srow * 2048 + scol,        &Vs[0][srow * 64 + dcol]);
    gload_lds16(V + (size_t)(srow + 32) * 2048 + scol, &Vs[0][(srow + 32) * 64 + dcol]);
  }
  __syncthreads();

  for (int tk = 0; tk < NT; ++tk) {
    const int cur = tk & 1;
    if (tk < NT - 1) {
      const int k1 = (tk + 1) * 64;
      const unsigned short* Kg = K + (size_t)k1 * 64;
      const unsigned short* Vg = V + k1;
      gload_lds16(Kg + (size_t)srow * 64 + scol,        &Ks[cur ^ 1][srow * 64 + dcol]);
      gload_lds16(Kg + (size_t)(srow + 32) * 64 + scol, &Ks[cur ^ 1][(srow + 32) * 64 + dcol]);
      gload_lds16(Vg + (size_t)srow * 2048 + scol,        &Vs[cur ^ 1][srow * 64 + dcol]);
      gload_lds16(Vg + (size_t)(srow + 32) * 2048 + scol, &Vs[cur ^ 1][(srow + 32) * 64 + dcol]);
    }

    // QK^T: sa[m2] = sum_kd mfma32x32x16(K_frag, Q_frag)
    f32x16 sa[2] = {};
    __builtin_amdgcn_s_setprio(1);
#pragma unroll
    for (int m2 = 0; m2 < 2; ++m2)
#pragma unroll
      for (int kd = 0; kd < 4; ++kd) {
        const bf16x8 kf = *(const bf16x8_a*)
            &Ks[cur][(m2 * 32 + l31) * 64 + (((kd * 2 + lh) ^ (l & 7)) << 3)];
        sa[m2] = __builtin_amdgcn_mfma_f32_32x32x16_bf16(kf, qf[kd], sa[m2], 0, 0, 0);
      }
    __builtin_amdgcn_s_setprio(0);

    // hoist V nb=0 fragments (LDS latency hides under the exp chain; T14)
    bf16x8 vf0[4];
#pragma unroll
    for (int ksI = 0; ksI < 4; ++ksI)
      vf0[ksI] = *(const bf16x8_a*)&Vs[cur][l31 * 64 + (((ksI * 2 + lh) ^ (l & 7)) << 3)];

    // softmax numerator (static shift -16, r12-exact) -> pack into PV A-fragments
    unsigned int pk[2][8];
#pragma unroll
    for (int m2 = 0; m2 < 2; ++m2) {
      float p[16];
#pragma unroll
      for (int r = 0; r < 16; ++r) p[r] = fast_exp2(sa[m2][r] + SHIFT);
#pragma unroll
      for (int u = 0; u < 8; ++u) pk[m2][u] = pktrunc(p[2 * u], p[2 * u + 1]);
    }

    // PV + rowsum: A = packed P (in-register), B = V from LDS / ones
    union { unsigned int u[4]; bf16x8 v; } pa[4];
#pragma unroll
    for (int m2 = 0; m2 < 2; ++m2)
#pragma unroll
      for (int ks2 = 0; ks2 < 2; ++ks2) {
        const int ksI = m2 * 2 + ks2;
        pa[ksI].u[0] = pk[m2][ks2 * 4 + 0];
        pa[ksI].u[1] = pk[m2][ks2 * 4 + 1];
        pa[ksI].u[2] = pk[m2][ks2 * 4 + 2];
        pa[ksI].u[3] = pk[m2][ks2 * 4 + 3];
      }
    __builtin_amdgcn_s_setprio(1);
#pragma unroll
    for (int ksI = 0; ksI < 4; ++ksI) {
      const bf16x8 vf1 = *(const bf16x8_a*)
          &Vs[cur][(32 + l31) * 64 + (((ksI * 2 + lh) ^ (l & 7)) << 3)];
      o32[0] = __builtin_amdgcn_mfma_f32_32x32x16_bf16(pa[ksI].v, vf0[ksI], o32[0], 0, 0, 0);
      lsum   = __builtin_amdgcn_mfma_f32_32x32x16_bf16(pa[ksI].v, ones,     lsum,   0, 0, 0);
      o32[1] = __builtin_amdgcn_mfma_f32_32x32x16_bf16(pa[ksI].v, vf1,      o32[1], 0, 0, 0);
    }
    __builtin_amdgcn_s_setprio(0);

    __syncthreads();
  }

  if (SPLIT == 2) {
    const size_t pbase = ((size_t)(half * 32 + bh) * 2048 + qbase);
#pragma unroll
    for (int nb = 0; nb < 2; ++nb)
#pragma unroll
      for (int r = 0; r < 16; ++r) {
        const int qrow = (r & 3) + 8 * (r >> 2) + 4 * lh;
        Opart[(pbase + qrow) * 64 + nb * 32 + l31] = f2bf(o32[nb][r]);
      }
    if (l31 == 0) {                       // lanes 0 and 32 cover the 32 q-rows
#pragma unroll
      for (int r = 0; r < 16; ++r)
        lpart[pbase + (r & 3) + 8 * (r >> 2) + 4 * lh] = lsum[r];
    }
  } else {
    // lsum is in o32's register layout: normalize with zero shuffles
#pragma unroll
    for (int nb = 0; nb < 2; ++nb)
#pragma unroll
      for (int r = 0; r < 16; ++r) {
        const int qrow = (r & 3) + 8 * (r >> 2) + 4 * lh;
        const size_t row = (size_t)b * 2048 + qbase + qrow;
        AO[row * 1024 + h * 64 + nb * 32 + l31] = f2bf(o32[nb][r] / lsum[r]);
      }
  }
}

// merge kv-split partials: AO = (O0 + O1) / (l0 + l1)
__global__ __launch_bounds__(256) void merge_k(const unsigned short* __restrict__ Opart,
                                               const float* __restrict__ lpart,
                                               unsigned short* __restrict__ AO) {
  const int u = blockIdx.x * 256 + threadIdx.x;   // 524288 threads
  const int c8 = u & 7, s = (u >> 3) & 2047, bh = u >> 14;
  const int b = bh >> 4, h = bh & 15;
  const size_t r0 = (size_t)bh * 2048 + s;
  const size_t r1 = (size_t)(32 + bh) * 2048 + s;
  const bf16x8 a0 = *(const bf16x8_a*)(Opart + r0 * 64 + c8 * 8);
  const bf16x8 a1 = *(const bf16x8_a*)(Opart + r1 * 64 + c8 * 8);
  const float inv = 1.0f / (lpart[r0] + lpart[r1]);
  bf16x8 oo;
#pragma unroll
  for (int i = 0; i < 8; ++i)
    oo[i] = (short)f2bf((bf2f((unsigned short)a0[i]) + bf2f((unsigned short)a1[i])) * inv);
  *(bf16x8_a*)(AO + ((size_t)b * 2048 + s) * 1024 + h * 64 + c8 * 8) = oo;
}

// ---------------- launcher ----------------
extern "C" void kernel_launch(void* const* d_in, const int* in_sizes, int n_in,
                              void* d_out, int out_size, void* d_ws, size_t ws_size,
                              hipStream_t stream) {
  const float* query = (const float*)d_in[0];
  // d_in[1]=key, d_in[2]=value: unused (reference derives q,k,v from query)
  const float* W_qkv = (const float*)d_in[3];
  const float* b_qkv = (const float*)d_in[4];
  const float* W_out = (const float*)d_in[5];
  const float* b_out = (const float*)d_in[6];
  float* out = (float*)d_out;
  char* ws = (char*)d_ws;

  // ws layout: [Xb/AO 8MB][WqkvT 6MB][WoutT 2MB][qb 8MB][kb 8MB][vT 8MB] = 41.94MB
  // + optional kv-split partials: [Opart 16.78MB][lpart 0.5MB] -> 59.24MB
  unsigned short* Xb    = (unsigned short*)(ws);
  unsigned short* WqkvT = (unsigned short*)(ws + 8388608);
  unsigned short* WoutT = (unsigned short*)(ws + 14680064);
  unsigned short* qb    = (unsigned short*)(ws + 16777216);
  unsigned short* kb    = (unsigned short*)(ws + 25165824);
  unsigned short* vT    = (unsigned short*)(ws + 33554432);
  unsigned short* Opart = (unsigned short*)(ws + 41943040);
  float*          lpart = (float*)(ws + 58720256);
  const bool split2 = ws_size >= 59244544;
  unsigned short* AO    = Xb;  // Xb dead after gemm1; reuse for attention output

  prep_k<<<8192, 256, 0, stream>>>((const float4*)query, (ushort4*)Xb,
                                   W_qkv, WqkvT, W_out, WoutT);
  gemm_bt<1, 128><<<768, 256, 0, stream>>>(Xb, WqkvT, b_qkv, nullptr, qb, kb, vT,
                                           4096, 3072, 1024);
  if (split2) {
    attn_k<2><<<1024, 256, 0, stream>>>(qb, kb, vT, nullptr, Opart, lpart);
    merge_k<<<2048, 256, 0, stream>>>(Opart, lpart, AO);
  } else {
    attn_k<1><<<512, 256, 0, stream>>>(qb, kb, vT, AO, nullptr, nullptr);
  }
  gemm_bt<0, 64><<<512, 256, 0, stream>>>(AO, WoutT, b_out, out, nullptr, nullptr, nullptr,
                                          4096, 1024, 1024);
}

// Round 16
// 116.481 us; speedup vs baseline: 1.0234x; 1.0234x over previous
//
#include <hip/hip_runtime.h>
#include <stdint.h>

#define DEV static __device__ __forceinline__

typedef __attribute__((ext_vector_type(4))) float f32x4;
typedef __attribute__((ext_vector_type(16))) float f32x16;
typedef __attribute__((ext_vector_type(8))) short bf16x8;               // 8 bf16 in 4 VGPR (guide §3)
typedef bf16x8 __attribute__((may_alias)) bf16x8_a;
typedef __attribute__((ext_vector_type(2))) unsigned int u32x2;
typedef u32x2 __attribute__((may_alias)) u32x2_a;

// f32 -> bf16 RNE, manual bit math (PROVEN; round-6's inline-asm cvt_pk NaN'd)
DEV unsigned short f2bf(float f) {
  union { float f; unsigned int u; } v; v.f = f;
  return (unsigned short)((v.u + 0x7FFFu + ((v.u >> 16) & 1u)) >> 16);
}

DEV float bf2f(unsigned short s) {
  union { unsigned int u; float f; } v; v.u = ((unsigned int)s) << 16;
  return v.f;
}

DEV float fast_exp2(float x) {            // native v_exp_f32 = 2^x
  float r;
  asm("v_exp_f32 %0, %1" : "=v"(r) : "v"(x));
  return r;
}

// pack two POSITIVE f32 -> (bf16_trunc(hi)<<16)|bf16_trunc(lo), ONE v_perm_b32.
// Truncation error cancels in O/l since the l-denominator (MFMA rowsum) is computed
// from the SAME truncated values.
DEV unsigned int pktrunc(float lo, float hi) {
  union { float f; unsigned int u; } a, b; a.f = lo; b.f = hi;
  return __builtin_amdgcn_perm(b.u, a.u, 0x07060302u);  // bytes: b3 b2 a3 a2
}

DEV void gload_lds16(const void* g, void* l) {
  __builtin_amdgcn_global_load_lds(
      (const __attribute__((address_space(1))) unsigned int*)g,
      (__attribute__((address_space(3))) unsigned int*)l, 16, 0, 0);
}

// ---------------- fused prep kernel: cast + 2 transposes in one launch ----------------
DEV void transpose_body(const float* __restrict__ in, unsigned short* __restrict__ out,
                        int R, int C, int bx, int by, int t, float (*tile)[33]) {
  const int r = t >> 3, c4 = (t & 7) << 2;
  const int tr = by << 5, tc = bx << 5;
  const float4 v = *(const float4*)(in + (size_t)(tr + r) * C + tc + c4);
  tile[r][c4] = v.x; tile[r][c4 + 1] = v.y; tile[r][c4 + 2] = v.z; tile[r][c4 + 3] = v.w;
  __syncthreads();
  ushort4 o;
  o.x = f2bf(tile[c4][r]); o.y = f2bf(tile[c4 + 1][r]);
  o.z = f2bf(tile[c4 + 2][r]); o.w = f2bf(tile[c4 + 3][r]);
  *(ushort4*)(out + (size_t)(tc + r) * R + tr + c4) = o;
}

__global__ __launch_bounds__(256) void prep_k(const float4* __restrict__ q4,
                                              ushort4* __restrict__ Xb,
                                              const float* __restrict__ Wqkv,
                                              unsigned short* __restrict__ WqkvT,
                                              const float* __restrict__ Wout,
                                              unsigned short* __restrict__ WoutT) {
  __shared__ float tile[32][33];
  const int t = threadIdx.x, bid = blockIdx.x;
  if (bid < 4096) {                       // cast query fp32 -> bf16 (4M elems)
    const int i = bid * 256 + t;
    float4 f = q4[i];
    ushort4 o; o.x = f2bf(f.x); o.y = f2bf(f.y); o.z = f2bf(f.z); o.w = f2bf(f.w);
    Xb[i] = o;
  } else if (bid < 4096 + 3072) {         // W_qkv [1024][3072] -> bf16 [3072][1024]
    const int id = bid - 4096;
    transpose_body(Wqkv, WqkvT, 1024, 3072, id % 96, id / 96, t, tile);
  } else {                                // W_out [1024][1024] -> bf16 [1024][1024]^T
    const int id = bid - 4096 - 3072;
    transpose_body(Wout, WoutT, 1024, 1024, id & 31, id >> 5, t, tile);
  }
}

// ---------------- GEMM (m97/m103 structure): C[M,N] = A[M,K] * BT[N,K]^T ----------------
// TM=128 x BN, BK=64, SINGLE-buffered LDS, 2 barriers/iter — the 912 TF @4096^3
// structure (m103). 4 waves as 2x2; 32 MFMA + 16 b128 per wave per K-step.
// Chunk-XOR swizzle (rule #21). XCD swizzle: bid%8 = XCD owns 4 m-panels.
// EPI==1 scatter: q (x0.125*log2e) / k [B,H,S,64] / V in MFMA-FRAGMENT ORDER:
// vfrag[bh][tile][nb][ksI] = 1KB lane-linear block; lane (lh,l31) 16B holds
// V[kv = tile*64 + (j&3)+4*lh+8*(j>>2)+16*ksI][d = nb*32+l31] for j=0..7
// (kappa derived from the verified tau layout). attn then loads V with ONE
// coalesced global_load_dwordx4 per fragment — V leaves the LDS pipe entirely.
template <int EPI, int BN>
__global__ __launch_bounds__(256, 3) void gemm_bt(const unsigned short* __restrict__ A,
                                                  const unsigned short* __restrict__ BT,
                                                  const float* __restrict__ bias,
                                                  float* __restrict__ Cout,
                                                  unsigned short* __restrict__ q_buf,
                                                  unsigned short* __restrict__ k_buf,
                                                  unsigned short* __restrict__ vfrag,
                                                  int M, int N, int K) {
  constexpr int NI = BN / 32;                   // n-frags per wave (wave grid 2x2)
  constexpr int NW = BN / 2;                    // cols per wave
  __shared__ unsigned short As[128 * 64];       // 16 KB, chunk-swizzled
  __shared__ unsigned short Bs[BN * 64];        // 16 or 8 KB
  const int t = threadIdx.x, w = t >> 6, l = t & 63;
  const int wm = w >> 1, wn = w & 1;
  const int lg = l >> 4, ln = l & 15;

  const int xcd = blockIdx.x & 7, jb = blockIdx.x >> 3;
  const int m0 = (xcd * 4 + (jb & 3)) * 128;    // 32 m-panels = 8 XCD x 4
  const int n0 = (jb >> 2) * BN;

  // staging: thread covers 16B chunk; row = (t>>3)+j*32, source chunk inverse-swizzled
  const int sch = (t & 7) ^ ((t >> 3) & 7);

  f32x4 acc[4][NI] = {};

#define STAGE97(k0)                                                                      \
  do {                                                                                   \
    _Pragma("unroll")                                                                    \
    for (int j = 0; j < 4; ++j)                                                          \
      gload_lds16(A + (size_t)(m0 + (t >> 3) + j * 32) * K + (k0) + sch * 8,             \
                  &As[((t >> 3) + j * 32) * 64 + (t & 7) * 8]);                          \
    _Pragma("unroll")                                                                    \
    for (int j = 0; j < BN / 32; ++j)                                                    \
      gload_lds16(BT + (size_t)(n0 + (t >> 3) + j * 32) * K + (k0) + sch * 8,            \
                  &Bs[((t >> 3) + j * 32) * 64 + (t & 7) * 8]);                          \
  } while (0)

  for (int kt = 0; kt < K; kt += 64) {
    STAGE97(kt);
    __syncthreads();                     // vmcnt drained -> tile resident
#pragma unroll
    for (int kk = 0; kk < 2; ++kk) {
      bf16x8 af[4], bfr[NI];
#pragma unroll
      for (int mi = 0; mi < 4; ++mi)
        af[mi] = *(const bf16x8_a*)&As[(wm * 64 + mi * 16 + ln) * 64 +
                                       (((kk * 4 + lg) ^ (ln & 7)) << 3)];
#pragma unroll
      for (int ni = 0; ni < NI; ++ni)
        bfr[ni] = *(const bf16x8_a*)&Bs[(wn * NW + ni * 16 + ln) * 64 +
                                        (((kk * 4 + lg) ^ (ln & 7)) << 3)];
#pragma unroll
      for (int mi = 0; mi < 4; ++mi)
#pragma unroll
        for (int ni = 0; ni < NI; ++ni)
          acc[mi][ni] = __builtin_amdgcn_mfma_f32_16x16x32_bf16(af[mi], bfr[ni], acc[mi][ni], 0, 0, 0);
    }
    __syncthreads();                     // reads done -> tile reusable
  }
#undef STAGE97

  // epilogue: C/D layout col = lane&15, row = (lane>>4)*4 + reg  (m89-verified)
#pragma unroll
  for (int ni = 0; ni < NI; ++ni) {
    const int c = n0 + wn * NW + ni * 16 + ln;
    const float bv = bias[c];
    if (EPI == 1) {
      const int which = c >> 10;          // 0:q 1:k 2:v   (wave-uniform)
      const int h = (c >> 6) & 15;
      const int d = c & 63;
#pragma unroll
      for (int mi = 0; mi < 4; ++mi) {
        const int mrow = m0 + wm * 64 + mi * 16 + lg * 4;
        const int b = mrow >> 11, s = mrow & 2047;
        const size_t bh = (size_t)(b * 16 + h);
        f32x4 v = acc[mi][ni];
        if (which == 0) {
          const float QSCALE = 0.125f * 1.44269504088896340736f;  // hd^-0.5 * log2(e)
          unsigned short* dst = q_buf + (bh * 2048 + s) * 64 + d;
#pragma unroll
          for (int r = 0; r < 4; ++r) dst[(size_t)r * 64] = f2bf((v[r] + bv) * QSCALE);
        } else if (which == 1) {
          unsigned short* dst = k_buf + (bh * 2048 + s) * 64 + d;
#pragma unroll
          for (int r = 0; r < 4; ++r) dst[(size_t)r * 64] = f2bf(v[r] + bv);
        } else {
          // fragment-order scatter: 4 consecutive kv (s..s+3) = bits0-1 of kappa.
          // block = [bh][tile=s>>6][nb=d>>5][ksI=(s>>4)&3] (512 shorts);
          // offset = lh(=(s>>2)&1)*256 + (d&31)*8 + jhi(=(s>>3)&1)*4.
          unsigned short* dst = vfrag +
              (((bh * 32 + (size_t)(s >> 6)) * 2 + ((d >> 5) & 1)) * 4 + ((s >> 4) & 3)) * 512 +
              ((s >> 2) & 1) * 256 + (d & 31) * 8 + ((s >> 3) & 1) * 4;
          ushort4 o4;
          o4.x = f2bf(v[0] + bv); o4.y = f2bf(v[1] + bv); o4.z = f2bf(v[2] + bv); o4.w = f2bf(v[3] + bv);
          *(ushort4*)dst = o4;
        }
      }
    } else {
#pragma unroll
      for (int mi = 0; mi < 4; ++mi) {
        const int mrow = m0 + wm * 64 + mi * 16 + lg * 4;
        f32x4 v = acc[mi][ni];
#pragma unroll
        for (int r = 0; r < 4; ++r) Cout[(size_t)(mrow + r) * N + c] = v[r] + bv;
      }
    }
  }
}

// ---------------- flash attention (round 16: V via fragment-order global loads) ----------------
// r12 base (46us proven; setprio REVERTED — r15: -16%). NEW: V is read straight from
// global in MFMA-fragment order (one coalesced dwordx4 per fragment, L1/L2-resident,
// 4 waves/block share lines) — V leaves the LDS pipe entirely: LDS reads/wave/tile
// halve (16->8), V staging removed, LDS 32->16KB. K stays LDS-staged (dbuf, swizzled).
// 32x32 swapped QK^T, in-register P, MFMA rowsum, static shift -16, XCD swizzle.
template <int SPLIT>
__global__ __launch_bounds__(256, 4) void attn_k(const unsigned short* __restrict__ Qb,
                                                 const unsigned short* __restrict__ Kb,
                                                 const unsigned short* __restrict__ Vf,
                                                 unsigned short* __restrict__ AO,
                                                 unsigned short* __restrict__ Opart,
                                                 float* __restrict__ lpart) {
  constexpr int NT = 32 / SPLIT;              // KV tiles per block
  const float SHIFT = -16.0f;                 // static softmax shift (exact; scores ~N(0,1.44^2))
  __shared__ unsigned short Ks[2][64 * 64];   // 16 KB (K only)

  const int t = threadIdx.x, w = t >> 6, l = t & 63;
  const int l31 = l & 31, lh = l >> 5;
  const int xcd = blockIdx.x & 7, idx = blockIdx.x >> 3;
  const int bh = xcd * 4 + (idx & 3);                    // [0,32)
  const int qt = (SPLIT == 2) ? ((idx >> 2) & 15) : (idx >> 2);
  const int half = (SPLIT == 2) ? (idx >> 6) : 0;
  const int b = bh >> 4, h = bh & 15;
  const unsigned short* Q = Qb + (size_t)bh * 2048 * 64;
  const unsigned short* K = Kb + (size_t)bh * 2048 * 64 + (size_t)half * NT * 64 * 64;
  const unsigned short* V = Vf + ((size_t)bh * 32 + half * NT) * 4096;   // fragment-order
  const int qbase = qt * 128 + w * 32;

  const int srow = t >> 3;                                // 0..31 (+32 second chunk)
  const int scol = ((t & 7) ^ (srow & 7)) << 3;           // swizzled source col
  const int dcol = (t & 7) << 3;                          // linear LDS col

  // Q fragments (B-operand): lane holds q-col = l31, d = kd*16 + lh*8 + 0..7
  bf16x8 qf[4];
#pragma unroll
  for (int kd = 0; kd < 4; ++kd)
    qf[kd] = *(const bf16x8_a*)(Q + (size_t)(qbase + l31) * 64 + kd * 16 + lh * 8);

  bf16x8 ones;
#pragma unroll
  for (int i = 0; i < 8; ++i) ones[i] = (short)0x3F80;    // bf16 1.0

  f32x16 o32[2] = {};
  f32x16 lsum = {};

  {
    gload_lds16(K + (size_t)srow * 64 + scol,        &Ks[0][srow * 64 + dcol]);
    gload_lds16(K + (size_t)(srow + 32) * 64 + scol, &Ks[0][(srow + 32) * 64 + dcol]);
  }
  __syncthreads();

  for (int tk = 0; tk < NT; ++tk) {
    const int cur = tk & 1;
    if (tk < NT - 1) {
      const unsigned short* Kg = K + (size_t)(tk + 1) * 64 * 64;
      gload_lds16(Kg + (size_t)srow * 64 + scol,        &Ks[cur ^ 1][srow * 64 + dcol]);
      gload_lds16(Kg + (size_t)(srow + 32) * 64 + scol, &Ks[cur ^ 1][(srow + 32) * 64 + dcol]);
    }

    // QK^T: sa[m2] = sum_kd mfma32x32x16(K_frag, Q_frag)
    f32x16 sa[2] = {};
#pragma unroll
    for (int m2 = 0; m2 < 2; ++m2)
#pragma unroll
      for (int kd = 0; kd < 4; ++kd) {
        const bf16x8 kf = *(const bf16x8_a*)
            &Ks[cur][(m2 * 32 + l31) * 64 + (((kd * 2 + lh) ^ (l & 7)) << 3)];
        sa[m2] = __builtin_amdgcn_mfma_f32_32x32x16_bf16(kf, qf[kd], sa[m2], 0, 0, 0);
      }

    // ALL V fragments: coalesced global loads (L1/L2-hit), issued before the exp
    // chain so their latency hides under softmax VALU (T14)
    const unsigned short* Vt_ = V + (size_t)tk * 4096;
    bf16x8 vf[2][4];
#pragma unroll
    for (int nb = 0; nb < 2; ++nb)
#pragma unroll
      for (int ksI = 0; ksI < 4; ++ksI)
        vf[nb][ksI] = *(const bf16x8_a*)(Vt_ + ((nb * 4 + ksI) << 9) + l * 8);

    // softmax numerator (static shift) -> pack into PV A-fragments
    unsigned int pk[2][8];
#pragma unroll
    for (int m2 = 0; m2 < 2; ++m2) {
      float p[16];
#pragma unroll
      for (int r = 0; r < 16; ++r) p[r] = fast_exp2(sa[m2][r] + SHIFT);
#pragma unroll
      for (int u = 0; u < 8; ++u) pk[m2][u] = pktrunc(p[2 * u], p[2 * u + 1]);
    }

    // PV + rowsum: A = packed P (in-register), B = V fragments / ones
    union { unsigned int u[4]; bf16x8 v; } pa[4];
#pragma unroll
    for (int m2 = 0; m2 < 2; ++m2)
#pragma unroll
      for (int ks2 = 0; ks2 < 2; ++ks2) {
        const int ksI = m2 * 2 + ks2;
        pa[ksI].u[0] = pk[m2][ks2 * 4 + 0];
        pa[ksI].u[1] = pk[m2][ks2 * 4 + 1];
        pa[ksI].u[2] = pk[m2][ks2 * 4 + 2];
        pa[ksI].u[3] = pk[m2][ks2 * 4 + 3];
      }
#pragma unroll
    for (int ksI = 0; ksI < 4; ++ksI) {
      o32[0] = __builtin_amdgcn_mfma_f32_32x32x16_bf16(pa[ksI].v, vf[0][ksI], o32[0], 0, 0, 0);
      lsum   = __builtin_amdgcn_mfma_f32_32x32x16_bf16(pa[ksI].v, ones,       lsum,   0, 0, 0);
      o32[1] = __builtin_amdgcn_mfma_f32_32x32x16_bf16(pa[ksI].v, vf[1][ksI], o32[1], 0, 0, 0);
    }

    __syncthreads();
  }

  if (SPLIT == 2) {
    const size_t pbase = ((size_t)(half * 32 + bh) * 2048 + qbase);
#pragma unroll
    for (int nb = 0; nb < 2; ++nb)
#pragma unroll
      for (int r = 0; r < 16; ++r) {
        const int qrow = (r & 3) + 8 * (r >> 2) + 4 * lh;
        Opart[(pbase + qrow) * 64 + nb * 32 + l31] = f2bf(o32[nb][r]);
      }
    if (l31 == 0) {                       // lanes 0 and 32 cover the 32 q-rows
#pragma unroll
      for (int r = 0; r < 16; ++r)
        lpart[pbase + (r & 3) + 8 * (r >> 2) + 4 * lh] = lsum[r];
    }
  } else {
    // lsum is in o32's register layout: normalize with zero shuffles
#pragma unroll
    for (int nb = 0; nb < 2; ++nb)
#pragma unroll
      for (int r = 0; r < 16; ++r) {
        const int qrow = (r & 3) + 8 * (r >> 2) + 4 * lh;
        const size_t row = (size_t)b * 2048 + qbase + qrow;
        AO[row * 1024 + h * 64 + nb * 32 + l31] = f2bf(o32[nb][r] / lsum[r]);
      }
  }
}

// merge kv-split partials: AO = (O0 + O1) / (l0 + l1)
__global__ __launch_bounds__(256) void merge_k(const unsigned short* __restrict__ Opart,
                                               const float* __restrict__ lpart,
                                               unsigned short* __restrict__ AO) {
  const int u = blockIdx.x * 256 + threadIdx.x;   // 524288 threads
  const int c8 = u & 7, s = (u >> 3) & 2047, bh = u >> 14;
  const int b = bh >> 4, h = bh & 15;
  const size_t r0 = (size_t)bh * 2048 + s;
  const size_t r1 = (size_t)(32 + bh) * 2048 + s;
  const bf16x8 a0 = *(const bf16x8_a*)(Opart + r0 * 64 + c8 * 8);
  const bf16x8 a1 = *(const bf16x8_a*)(Opart + r1 * 64 + c8 * 8);
  const float inv = 1.0f / (lpart[r0] + lpart[r1]);
  bf16x8 oo;
#pragma unroll
  for (int i = 0; i < 8; ++i)
    oo[i] = (short)f2bf((bf2f((unsigned short)a0[i]) + bf2f((unsigned short)a1[i])) * inv);
  *(bf16x8_a*)(AO + ((size_t)b * 2048 + s) * 1024 + h * 64 + c8 * 8) = oo;
}

// ---------------- launcher ----------------
extern "C" void kernel_launch(void* const* d_in, const int* in_sizes, int n_in,
                              void* d_out, int out_size, void* d_ws, size_t ws_size,
                              hipStream_t stream) {
  const float* query = (const float*)d_in[0];
  // d_in[1]=key, d_in[2]=value: unused (reference derives q,k,v from query)
  const float* W_qkv = (const float*)d_in[3];
  const float* b_qkv = (const float*)d_in[4];
  const float* W_out = (const float*)d_in[5];
  const float* b_out = (const float*)d_in[6];
  float* out = (float*)d_out;
  char* ws = (char*)d_ws;

  // ws layout: [Xb/AO 8MB][WqkvT 6MB][WoutT 2MB][qb 8MB][kb 8MB][vfrag 8MB] = 41.94MB
  // + optional kv-split partials: [Opart 16.78MB][lpart 0.5MB] -> 59.24MB
  unsigned short* Xb    = (unsigned short*)(ws);
  unsigned short* WqkvT = (unsigned short*)(ws + 8388608);
  unsigned short* WoutT = (unsigned short*)(ws + 14680064);
  unsigned short* qb    = (unsigned short*)(ws + 16777216);
  unsigned short* kb    = (unsigned short*)(ws + 25165824);
  unsigned short* vfrag = (unsigned short*)(ws + 33554432);
  unsigned short* Opart = (unsigned short*)(ws + 41943040);
  float*          lpart = (float*)(ws + 58720256);
  const bool split2 = ws_size >= 59244544;
  unsigned short* AO    = Xb;  // Xb dead after gemm1; reuse for attention output

  prep_k<<<8192, 256, 0, stream>>>((const float4*)query, (ushort4*)Xb,
                                   W_qkv, WqkvT, W_out, WoutT);
  gemm_bt<1, 128><<<768, 256, 0, stream>>>(Xb, WqkvT, b_qkv, nullptr, qb, kb, vfrag,
                                           4096, 3072, 1024);
  if (split2) {
    attn_k<2><<<1024, 256, 0, stream>>>(qb, kb, vfrag, nullptr, Opart, lpart);
    merge_k<<<2048, 256, 0, stream>>>(Opart, lpart, AO);
  } else {
    attn_k<1><<<512, 256, 0, stream>>>(qb, kb, vfrag, AO, nullptr, nullptr);
  }
  gemm_bt<0, 64><<<512, 256, 0, stream>>>(AO, WoutT, b_out, out, nullptr, nullptr, nullptr,
                                          4096, 1024, 1024);
}